// Round 6
// baseline (107.597 us; speedup 1.0000x reference)
//
#include <hip/hip_runtime.h>

// DualCompressor: y_fwd[v,m] = log(sum_k exp(d_out_t[v,k] + alpha_fwd[m,k]))
//                 y_bwd[v,m] = log(sum_k exp(d_in_t[v,k]  + alpha_bwd[m,k]))
// SIGMA = 1.0.   log(sum_k exp(phi_k)*exp(alpha_mk)).
//
// R6: R5's SGPR-alpha FMA loop kept (prep kernel -> exp(alpha) table in d_ws,
// wave-uniform indexing -> s_load + v_fmac w/ SGPR operand). New: the global
// read is now perfectly coalesced. R5 loaded lane=row strided 256 B (64 cache
// lines per instruction -> ~3-4 us of VMEM-issue over the 10.2 us HBM floor;
// measured kernel ~14.2 us). Here each wave stages its 64 rows (contiguous
// 16 KB) with 16 coalesced dwordx4/thread into wave-private LDS (row-major,
// pad 65: write banks (row+4c)%32 -> 2-way; read banks (lane+k)%32 -> 2-way;
// both free), no barrier needed (same-wave ds ordering), then lane reads its
// own row + exp + 1024 FMA.
//
// Block = 128 = 2 waves (c = wave id) over the same 64 rows -> LDS 33.3 KB
// -> 4 blocks/CU = 8 waves/CU; 64 outstanding KB of loads per CU covers HBM
// latency. Edge rows clamped at load (data garbage), guarded at store.

#define K_DIM 64
#define PAD   65

__global__ __launch_bounds__(256) void prep_ealpha_kernel(
    const float* __restrict__ alpha_fwd,
    const float* __restrict__ alpha_bwd,
    float* __restrict__ ea)
{
    int i = blockIdx.x * 256 + threadIdx.x;       // grid 8 -> i in 0..2047
    float a = (i < 1024) ? alpha_fwd[i] : alpha_bwd[i - 1024];
    ea[i] = __expf(a);
}

__global__ __launch_bounds__(128) void dual_compress_kernel(
    const float* __restrict__ d_out_t,
    const float* __restrict__ d_in_t,
    const float* __restrict__ ea,     // exp(alpha): [c][m][k], 2048 floats
    float* __restrict__ out, int V)
{
    __shared__ float stage[2][64 * PAD];          // wave-private halves

    int tid  = threadIdx.x;
    int lane = tid & 63;
    int w    = tid >> 6;        // wave id = compressor c (0=fwd, 1=bwd)
    int c    = w;
    int wavebase = blockIdx.x * 64;               // first row this wave stages
    const float* base = c ? d_in_t : d_out_t;

    // ---- coalesced stage: 16 KB contiguous global -> LDS (transpose to
    //      row-major pad-65). Lane addr stride 16 B -> 1 KB/instruction.
    float* st = stage[w];
    size_t maxoff = (size_t)V * K_DIM - 4;        // last valid float4 start
    #pragma unroll
    for (int j = 0; j < 16; ++j) {
        size_t eoff = (size_t)wavebase * K_DIM + (size_t)j * 256 + (size_t)lane * 4;
        if (eoff > maxoff) eoff = maxoff;         // last-block clamp only
        float4 q = *(const float4*)(base + eoff);
        int row = j * 4 + (lane >> 4);
        int col = (lane & 15) * 4;
        float* d = st + row * PAD + col;
        d[0] = q.x; d[1] = q.y; d[2] = q.z; d[3] = q.w;
    }
    // wave-private LDS + in-order ds ops -> no __syncthreads.

    // ---- own row -> regs, exp
    const float* my = st + lane * PAD;
    float e[64];
    #pragma unroll
    for (int k = 0; k < 64; ++k) e[k] = __expf(my[k]);

    // ---- 1024 v_fmac with SGPR alpha operand (wave-uniform table base)
    const float* eac = ea + __builtin_amdgcn_readfirstlane(c << 10);

    float acc[16];
    #pragma unroll
    for (int mi = 0; mi < 16; ++mi) acc[mi] = 0.0f;

    #pragma unroll
    for (int kc = 0; kc < 16; ++kc) {
        #pragma unroll
        for (int mi = 0; mi < 16; ++mi) {
            const float* arow = eac + mi * K_DIM + kc * 4;
            acc[mi] = fmaf(e[kc*4+0], arow[0], acc[mi]);
            acc[mi] = fmaf(e[kc*4+1], arow[1], acc[mi]);
            acc[mi] = fmaf(e[kc*4+2], arow[2], acc[mi]);
            acc[mi] = fmaf(e[kc*4+3], arow[3], acc[mi]);
        }
    }

    int v = wavebase + lane;
    if (v < V) {
        float* orow = out + ((size_t)c * V + v) * 16;
        #pragma unroll
        for (int i = 0; i < 4; ++i) {
            float4 y;
            y.x = __logf(acc[4*i+0]);
            y.y = __logf(acc[4*i+1]);
            y.z = __logf(acc[4*i+2]);
            y.w = __logf(acc[4*i+3]);
            ((float4*)orow)[i] = y;
        }
    }
}

extern "C" void kernel_launch(void* const* d_in, const int* in_sizes, int n_in,
                              void* d_out, int out_size, void* d_ws, size_t ws_size,
                              hipStream_t stream) {
    const float* d_out_t   = (const float*)d_in[0];
    const float* d_in_t    = (const float*)d_in[1];
    const float* alpha_fwd = (const float*)d_in[2];
    const float* alpha_bwd = (const float*)d_in[3];
    float* out = (float*)d_out;
    float* ea  = (float*)d_ws;            // 2048 floats of scratch

    int V = in_sizes[0] / K_DIM;          // 100000

    prep_ealpha_kernel<<<8, 256, 0, stream>>>(alpha_fwd, alpha_bwd, ea);

    int grid = (V + 63) / 64;             // 64 rows per block (both c's)
    dual_compress_kernel<<<grid, 128, 0, stream>>>(
        d_out_t, d_in_t, ea, out, V);
}